// Round 2
// baseline (364.106 us; speedup 1.0000x reference)
//
#include <hip/hip_runtime.h>
#include <math.h>

#define B 8
#define NQ 2048
#define NK 2048
#define XD 2
#define CIN 64
#define COUT 64

constexpr int QBLK    = 64;            // one query per lane
constexpr int NWAVE   = 8;             // waves per block, split keys
constexpr int THREADS = NWAVE * 64;    // 512
constexpr int KCHUNK  = NK / NWAVE;    // 256 keys per wave
constexpr int CCH     = 16;            // channel chunk for LDS reduction
constexpr float LOG2E = 1.44269504088896340736f;

// shared buffer aliasing: phase 1 uses pre[NK][4] (32 KiB), phase 2 reuses the
// same 32 KiB as red[NWAVE][CCH][QBLK]. Disjoint in time (syncthreads between).
__global__ __launch_bounds__(THREADS) void setconv_kernel(
    const float* __restrict__ keys,     // [B][NK][2]
    const float* __restrict__ queries,  // [B][NQ][2]
    const float* __restrict__ values,   // [B][NK][CIN]
    const float* __restrict__ wW,       // [2][2]
    const float* __restrict__ lsp,      // [1]
    const float* __restrict__ dW,       // [1]
    const float* __restrict__ db,       // [1]
    const float* __restrict__ rW,       // [COUT][CIN+1]
    const float* __restrict__ rb,       // [COUT]
    float* __restrict__ out)            // [B][NQ][COUT]
{
    __shared__ float smem[NK * 4];            // 32 KiB: pre[k][4] then red[w][c][q]
    __shared__ float tot[QBLK][CIN + 2];      // 16.9 KiB (stride 66 breaks pow2)
    __shared__ float esred[NWAVE][QBLK];      // 2 KiB
    __shared__ float qinfo[QBLK][2];          // inv_esum, density

    const int tid  = threadIdx.x;
    const int wave = tid >> 6;
    const int lane = tid & 63;

    const int bid = blockIdx.x;
    const int b   = bid / (NQ / QBLK);
    const int q0  = (bid % (NQ / QBLK)) * QBLK;
    const int q   = q0 + lane;

    // uniform scalar params
    const float W00 = wW[0], W01 = wW[1], W10 = wW[2], W11 = wW[3];
    const float xls = lsp[0] * 0.1f - 1.0f;
    const float sp  = (xls > 20.f) ? xls : log1pf(__expf(xls));
    const float sigma = 1e-5f + sp;
    const float s2  = (-0.5f / (sigma * sigma)) * LOG2E;  // log2-domain scale

    // ---- phase 0: per-key precompute into LDS ----
    // l*log2e = E_k + F_q + atil*aq + btil*bq
    //   a = W00*kx+W01*ky, b = W10*kx+W11*ky
    //   E_k = s2*(a^2+b^2), atil = -2*s2*a, btil = -2*s2*b, F_q = s2*(aq^2+bq^2)
    {
        const float* kb = keys + (size_t)b * NK * XD;
        #pragma unroll
        for (int r = 0; r < NK / THREADS; ++r) {
            const int k = tid + r * THREADS;
            const float kx = kb[k * 2 + 0];
            const float ky = kb[k * 2 + 1];
            const float a  = W00 * kx + W01 * ky;
            const float bb = W10 * kx + W11 * ky;
            float4 p;
            p.x = -2.f * s2 * a;
            p.y = -2.f * s2 * bb;
            p.z = s2 * (a * a + bb * bb);
            p.w = 0.f;
            reinterpret_cast<float4*>(smem)[k] = p;
        }
    }

    const float qx = queries[(size_t)(b * NQ + q) * XD + 0];
    const float qy = queries[(size_t)(b * NQ + q) * XD + 1];
    const float aq = W00 * qx + W01 * qy;
    const float bq = W10 * qx + W11 * qy;
    const float Fq = s2 * (aq * aq + bq * bq);

    __syncthreads();

    float acc[CIN];
    #pragma unroll
    for (int c = 0; c < CIN; ++c) acc[c] = 0.f;
    float esum = 0.f;

    const float* vb = values + (size_t)b * NK * CIN;
    const int k0 = wave * KCHUNK;
    const float4* pre4 = reinterpret_cast<const float4*>(smem);

    #pragma unroll 2
    for (int k = k0; k < k0 + KCHUNK; ++k) {
        const float4 p = pre4[k];                 // uniform LDS read (broadcast)
        float t = p.z + Fq;
        t = fmaf(p.y, bq, t);
        t = fmaf(p.x, aq, t);
        const float e = exp2f(t);                 // native v_exp_f32
        esum += e;
        const float4* v4 = reinterpret_cast<const float4*>(vb + (size_t)k * CIN);
        #pragma unroll
        for (int c4 = 0; c4 < CIN / 4; ++c4) {
            const float4 v = v4[c4];
            acc[c4 * 4 + 0] += e * v.x;
            acc[c4 * 4 + 1] += e * v.y;
            acc[c4 * 4 + 2] += e * v.z;
            acc[c4 * 4 + 3] += e * v.w;
        }
    }

    // ---- cross-wave reduction: red[w][c][q] layout, lane-contiguous ----
    float* red = smem;   // reuse: [NWAVE][CCH][QBLK]
    #pragma unroll
    for (int ch = 0; ch < CIN / CCH; ++ch) {
        __syncthreads();
        #pragma unroll
        for (int c = 0; c < CCH; ++c)
            red[(wave * CCH + c) * QBLK + lane] = acc[ch * CCH + c];
        __syncthreads();
        #pragma unroll
        for (int rr = 0; rr < 2; ++rr) {
            const int p  = tid + rr * THREADS;    // 0..1023
            const int qq = p & 63;
            const int cc = p >> 6;
            float s = 0.f;
            #pragma unroll
            for (int w = 0; w < NWAVE; ++w) s += red[(w * CCH + cc) * QBLK + qq];
            tot[qq][ch * CCH + cc] = s;
        }
    }

    // ---- esum reduction + per-query scalars ----
    __syncthreads();
    esred[wave][lane] = esum;
    __syncthreads();
    if (tid < QBLK) {
        float s = 0.f;
        #pragma unroll
        for (int w = 0; w < NWAVE; ++w) s += esred[w][tid];
        // density = sigmoid((-esum * dW + db) * 0.1)
        const float arg = ((-s) * dW[0] + db[0]) * 0.1f;
        qinfo[tid][1] = 1.f / (1.f + __expf(-arg));
        qinfo[tid][0] = 1.f / s;
    }
    __syncthreads();

    // ---- fused resizer epilogue (normalization folded in) ----
    {
        const int qq   = tid >> 3;                // 0..63
        const float invE = qinfo[qq][0];
        const float dens = qinfo[qq][1];
        float* orow = out + (size_t)(b * NQ + q0 + qq) * COUT;
        #pragma unroll
        for (int r = 0; r < 8; ++r) {
            const int o = (tid & 7) + r * 8;
            const float* wrow = rW + o * (CIN + 1);
            float sdot = 0.f;
            #pragma unroll 8
            for (int c = 0; c < CIN; ++c) sdot += tot[qq][c] * wrow[c];
            orow[o] = rb[o] + dens * wrow[CIN] + sdot * invE;
        }
    }
}

extern "C" void kernel_launch(void* const* d_in, const int* in_sizes, int n_in,
                              void* d_out, int out_size, void* d_ws, size_t ws_size,
                              hipStream_t stream) {
    const float* keys    = (const float*)d_in[0];
    const float* queries = (const float*)d_in[1];
    const float* values  = (const float*)d_in[2];
    const float* wW      = (const float*)d_in[3];
    const float* lsp     = (const float*)d_in[4];
    const float* dW      = (const float*)d_in[5];
    const float* db      = (const float*)d_in[6];
    const float* rW      = (const float*)d_in[7];
    const float* rb      = (const float*)d_in[8];
    float* out = (float*)d_out;

    dim3 grid(B * (NQ / QBLK));   // 256 blocks, 1 per CU
    setconv_kernel<<<grid, THREADS, 0, stream>>>(
        keys, queries, values, wW, lsp, dW, db, rW, rb, out);
}

// Round 3
// 307.802 us; speedup vs baseline: 1.1829x; 1.1829x over previous
//
#include <hip/hip_runtime.h>
#include <math.h>

#define B 8
#define NQ 2048
#define NK 2048
#define XD 2
#define CIN 64
#define COUT 64

constexpr int QBLK    = 64;            // one query per lane
constexpr int NWAVE   = 8;             // waves per block, split keys
constexpr int THREADS = NWAVE * 64;    // 512
constexpr int KCHUNK  = NK / NWAVE;    // 256 keys per wave
constexpr int CCH     = 16;            // channel chunk for LDS reduction
constexpr float LOG2E = 1.44269504088896340736f;

typedef float f32x16 __attribute__((ext_vector_type(16)));

// cross-wave reduction of one 16-channel chunk held in SSA vector ACCV
#define REDUCE_CHUNK(CH, ACCV)                                              \
  {                                                                         \
    __syncthreads();                                                        \
    float* wp = red + (wave * CCH) * QBLK + lane;                           \
    _Pragma("unroll")                                                       \
    for (int c = 0; c < CCH; ++c) wp[c * QBLK] = ACCV[c];                   \
    __syncthreads();                                                        \
    _Pragma("unroll")                                                       \
    for (int rr = 0; rr < 2; ++rr) {                                        \
      const int p  = tid + rr * THREADS;                                    \
      const int qq = p & 63;                                                \
      const int cc = p >> 6;                                                \
      float s = 0.f;                                                        \
      _Pragma("unroll")                                                     \
      for (int w = 0; w < NWAVE; ++w) s += red[(w * CCH + cc) * QBLK + qq]; \
      tot[qq][(CH) * CCH + cc] = s;                                         \
    }                                                                       \
  }

__global__ __launch_bounds__(THREADS) void setconv_kernel(
    const float* __restrict__ keys,     // [B][NK][2]
    const float* __restrict__ queries,  // [B][NQ][2]
    const float* __restrict__ values,   // [B][NK][CIN]
    const float* __restrict__ wW,       // [2][2]
    const float* __restrict__ lsp,      // [1]
    const float* __restrict__ dW,       // [1]
    const float* __restrict__ db,       // [1]
    const float* __restrict__ rW,       // [COUT][CIN+1]
    const float* __restrict__ rb,       // [COUT]
    float* __restrict__ out)            // [B][NQ][COUT]
{
    __shared__ float smem[NK * 4];            // 32 KiB: pre[k][4] then red[w][c][q]
    __shared__ float tot[QBLK][CIN + 2];      // stride 66 breaks pow2
    __shared__ float esred[NWAVE][QBLK];
    __shared__ float qinfo[QBLK][2];          // inv_esum, density

    const int tid  = threadIdx.x;
    const int wave = tid >> 6;
    const int lane = tid & 63;

    const int bid = blockIdx.x;
    const int b   = bid & 7;                  // batch == XCD (round-robin dispatch)
    const int q0  = (bid >> 3) * QBLK;
    const int q   = q0 + lane;

    // uniform scalar params
    const float W00 = wW[0], W01 = wW[1], W10 = wW[2], W11 = wW[3];
    const float xls = lsp[0] * 0.1f - 1.0f;
    const float sp  = (xls > 20.f) ? xls : log1pf(__expf(xls));
    const float sigma = 1e-5f + sp;
    const float s2  = (-0.5f / (sigma * sigma)) * LOG2E;  // log2-domain scale

    // ---- phase 0: per-key precompute into LDS ----
    // l*log2e = E_k + F_q + atil*aq + btil*bq
    {
        const float* kb = keys + (size_t)b * NK * XD;
        #pragma unroll
        for (int r = 0; r < NK / THREADS; ++r) {
            const int k = tid + r * THREADS;
            const float kx = kb[k * 2 + 0];
            const float ky = kb[k * 2 + 1];
            const float a  = W00 * kx + W01 * ky;
            const float bb = W10 * kx + W11 * ky;
            float4 p;
            p.x = -2.f * s2 * a;
            p.y = -2.f * s2 * bb;
            p.z = s2 * (a * a + bb * bb);
            p.w = 0.f;
            reinterpret_cast<float4*>(smem)[k] = p;
        }
    }

    const float qx = queries[(size_t)(b * NQ + q) * XD + 0];
    const float qy = queries[(size_t)(b * NQ + q) * XD + 1];
    const float aq = W00 * qx + W01 * qy;
    const float bq = W10 * qx + W11 * qy;
    const float Fq = s2 * (aq * aq + bq * bq);

    __syncthreads();

    // accumulators: SSA vectors, guaranteed registers (no alloca)
    f32x16 acc0 = 0.f, acc1 = 0.f, acc2 = 0.f, acc3 = 0.f;
    float esum = 0.f;

    const float* vb = values + (size_t)b * NK * CIN;
    const int k0 = wave * KCHUNK;
    const float4* pre4 = reinterpret_cast<const float4*>(smem);

    #pragma unroll 2
    for (int k = k0; k < k0 + KCHUNK; ++k) {
        const float4 p = pre4[k];                 // uniform LDS read (broadcast)
        const float t = fmaf(p.x, aq, fmaf(p.y, bq, p.z + Fq));
        const float e = exp2f(t);                 // native v_exp_f32
        esum += e;
        const f32x16* vr = reinterpret_cast<const f32x16*>(vb + (size_t)k * CIN);
        const f32x16 x0 = vr[0];
        const f32x16 x1 = vr[1];
        const f32x16 x2 = vr[2];
        const f32x16 x3 = vr[3];
        acc0 += x0 * e;
        acc1 += x1 * e;
        acc2 += x2 * e;
        acc3 += x3 * e;
    }

    // ---- cross-wave reduction: red[w][c][q] layout, lane-contiguous ----
    float* red = smem;   // reuse as [NWAVE][CCH][QBLK]
    REDUCE_CHUNK(0, acc0)
    REDUCE_CHUNK(1, acc1)
    REDUCE_CHUNK(2, acc2)
    REDUCE_CHUNK(3, acc3)

    // ---- esum reduction + per-query scalars ----
    __syncthreads();
    esred[wave][lane] = esum;
    __syncthreads();
    if (tid < QBLK) {
        float s = 0.f;
        #pragma unroll
        for (int w = 0; w < NWAVE; ++w) s += esred[w][tid];
        const float arg = ((-s) * dW[0] + db[0]) * 0.1f;
        qinfo[tid][1] = 1.f / (1.f + __expf(-arg));   // density channel
        qinfo[tid][0] = 1.f / s;                      // softmax denom
    }
    __syncthreads();

    // ---- fused resizer epilogue (normalization folded in) ----
    {
        const int qq   = tid >> 3;                // 0..63
        const float invE = qinfo[qq][0];
        const float dens = qinfo[qq][1];
        float* orow = out + (size_t)(b * NQ + q0 + qq) * COUT;
        #pragma unroll
        for (int r = 0; r < 8; ++r) {
            const int o = (tid & 7) + r * 8;
            const float* wrow = rW + o * (CIN + 1);
            float sdot = 0.f;
            #pragma unroll 8
            for (int c = 0; c < CIN; ++c) sdot += tot[qq][c] * wrow[c];
            orow[o] = rb[o] + dens * wrow[CIN] + sdot * invE;
        }
    }
}

extern "C" void kernel_launch(void* const* d_in, const int* in_sizes, int n_in,
                              void* d_out, int out_size, void* d_ws, size_t ws_size,
                              hipStream_t stream) {
    const float* keys    = (const float*)d_in[0];
    const float* queries = (const float*)d_in[1];
    const float* values  = (const float*)d_in[2];
    const float* wW      = (const float*)d_in[3];
    const float* lsp     = (const float*)d_in[4];
    const float* dW      = (const float*)d_in[5];
    const float* db      = (const float*)d_in[6];
    const float* rW      = (const float*)d_in[7];
    const float* rb      = (const float*)d_in[8];
    float* out = (float*)d_out;

    dim3 grid(B * (NQ / QBLK));   // 256 blocks
    setconv_kernel<<<grid, THREADS, 0, stream>>>(
        keys, queries, values, wW, lsp, dW, db, rW, rb, out);
}

// Round 4
// 304.042 us; speedup vs baseline: 1.1976x; 1.0124x over previous
//
#include <hip/hip_runtime.h>
#include <math.h>

#define B 8
#define NQ 2048
#define NK 2048
#define XD 2
#define CIN 64
#define COUT 64

constexpr int QBLK    = 64;            // one query per lane
constexpr int NWAVE   = 8;             // waves per block, split keys
constexpr int THREADS = NWAVE * 64;    // 512
constexpr int KCHUNK  = NK / NWAVE;    // 256 keys per wave
constexpr int CCH     = 16;            // channel chunk for LDS reduction
constexpr float LOG2E = 1.44269504088896340736f;

// 4 accumulator updates from one float4 value load (all names distinct scalars)
#define FMA4(J, A0, A1, A2, A3)                          \
  {                                                      \
    const float4 v = v4[J];                              \
    A0 = fmaf(e, v.x, A0);                               \
    A1 = fmaf(e, v.y, A1);                               \
    A2 = fmaf(e, v.z, A2);                               \
    A3 = fmaf(e, v.w, A3);                               \
  }

// cross-wave reduction of one 16-channel chunk (all LDS offsets compile-time)
#define REDUCE16(CH, A0, A1, A2, A3, A4, A5, A6, A7,                        \
                 A8, A9, A10, A11, A12, A13, A14, A15)                      \
  {                                                                         \
    __syncthreads();                                                        \
    float* wp = red + (wave * CCH) * QBLK + lane;                           \
    wp[0 * QBLK]  = A0;  wp[1 * QBLK]  = A1;                                \
    wp[2 * QBLK]  = A2;  wp[3 * QBLK]  = A3;                                \
    wp[4 * QBLK]  = A4;  wp[5 * QBLK]  = A5;                                \
    wp[6 * QBLK]  = A6;  wp[7 * QBLK]  = A7;                                \
    wp[8 * QBLK]  = A8;  wp[9 * QBLK]  = A9;                                \
    wp[10 * QBLK] = A10; wp[11 * QBLK] = A11;                               \
    wp[12 * QBLK] = A12; wp[13 * QBLK] = A13;                               \
    wp[14 * QBLK] = A14; wp[15 * QBLK] = A15;                               \
    __syncthreads();                                                        \
    _Pragma("unroll")                                                       \
    for (int rr = 0; rr < 2; ++rr) {                                        \
      const int p  = tid + rr * THREADS;                                    \
      const int qq = p & 63;                                                \
      const int cc = p >> 6;                                                \
      float s = 0.f;                                                        \
      _Pragma("unroll")                                                     \
      for (int w = 0; w < NWAVE; ++w) s += red[(w * CCH + cc) * QBLK + qq]; \
      tot[qq][(CH) * CCH + cc] = s;                                         \
    }                                                                       \
  }

__global__ __launch_bounds__(THREADS) void setconv_kernel(
    const float* __restrict__ keys,     // [B][NK][2]
    const float* __restrict__ queries,  // [B][NQ][2]
    const float* __restrict__ values,   // [B][NK][CIN]
    const float* __restrict__ wW,       // [2][2]
    const float* __restrict__ lsp,      // [1]
    const float* __restrict__ dW,       // [1]
    const float* __restrict__ db,       // [1]
    const float* __restrict__ rW,       // [COUT][CIN+1]
    const float* __restrict__ rb,       // [COUT]
    float* __restrict__ out)            // [B][NQ][COUT]
{
    __shared__ float smem[NK * 4];            // 32 KiB: pre[k][4] then red[w][c][q]
    __shared__ float tot[QBLK][CIN + 2];      // stride 66 breaks pow2
    __shared__ float esred[NWAVE][QBLK];
    __shared__ float qinfo[QBLK][2];          // inv_esum, density

    const int tid  = threadIdx.x;
    const int wave = tid >> 6;
    const int lane = tid & 63;

    const int bid = blockIdx.x;
    const int b   = bid & 7;                  // batch == XCD (L2 locality)
    const int q0  = (bid >> 3) * QBLK;
    const int q   = q0 + lane;

    // uniform scalar params
    const float W00 = wW[0], W01 = wW[1], W10 = wW[2], W11 = wW[3];
    const float xls = lsp[0] * 0.1f - 1.0f;
    const float sp  = (xls > 20.f) ? xls : log1pf(__expf(xls));
    const float sigma = 1e-5f + sp;
    const float s2  = (-0.5f / (sigma * sigma)) * LOG2E;  // log2-domain scale

    // ---- phase 0: per-key score coefficients into LDS ----
    // l*log2e = E_k + F_q + atil*aq + btil*bq
    {
        const float* kb = keys + (size_t)b * NK * XD;
        #pragma unroll
        for (int r = 0; r < NK / THREADS; ++r) {
            const int k = tid + r * THREADS;
            const float kx = kb[k * 2 + 0];
            const float ky = kb[k * 2 + 1];
            const float a  = W00 * kx + W01 * ky;
            const float bb = W10 * kx + W11 * ky;
            float4 p;
            p.x = -2.f * s2 * a;
            p.y = -2.f * s2 * bb;
            p.z = s2 * (a * a + bb * bb);
            p.w = 0.f;
            reinterpret_cast<float4*>(smem)[k] = p;
        }
    }

    const float qx = queries[(size_t)(b * NQ + q) * XD + 0];
    const float qy = queries[(size_t)(b * NQ + q) * XD + 1];
    const float aq = W00 * qx + W01 * qy;
    const float bq = W10 * qx + W11 * qy;
    const float Fq = s2 * (aq * aq + bq * bq);

    __syncthreads();

    // 64 accumulators as individually named scalars — nothing to demote
    float a0=0.f,a1=0.f,a2=0.f,a3=0.f,a4=0.f,a5=0.f,a6=0.f,a7=0.f;
    float a8=0.f,a9=0.f,a10=0.f,a11=0.f,a12=0.f,a13=0.f,a14=0.f,a15=0.f;
    float a16=0.f,a17=0.f,a18=0.f,a19=0.f,a20=0.f,a21=0.f,a22=0.f,a23=0.f;
    float a24=0.f,a25=0.f,a26=0.f,a27=0.f,a28=0.f,a29=0.f,a30=0.f,a31=0.f;
    float a32=0.f,a33=0.f,a34=0.f,a35=0.f,a36=0.f,a37=0.f,a38=0.f,a39=0.f;
    float a40=0.f,a41=0.f,a42=0.f,a43=0.f,a44=0.f,a45=0.f,a46=0.f,a47=0.f;
    float a48=0.f,a49=0.f,a50=0.f,a51=0.f,a52=0.f,a53=0.f,a54=0.f,a55=0.f;
    float a56=0.f,a57=0.f,a58=0.f,a59=0.f,a60=0.f,a61=0.f,a62=0.f,a63=0.f;
    float esum = 0.f;

    const float* vb = values + (size_t)b * NK * CIN;
    const int k0 = wave * KCHUNK;
    const float4* pre4 = reinterpret_cast<const float4*>(smem);

    #pragma unroll 2
    for (int k = k0; k < k0 + KCHUNK; ++k) {
        const float4 p = pre4[k];                 // uniform LDS read (broadcast)
        const float t = fmaf(p.x, aq, fmaf(p.y, bq, p.z + Fq));
        const float e = exp2f(t);                 // native v_exp_f32
        esum += e;
        const float4* v4 = reinterpret_cast<const float4*>(vb + (size_t)k * CIN);
        FMA4(0,  a0,  a1,  a2,  a3)
        FMA4(1,  a4,  a5,  a6,  a7)
        FMA4(2,  a8,  a9,  a10, a11)
        FMA4(3,  a12, a13, a14, a15)
        FMA4(4,  a16, a17, a18, a19)
        FMA4(5,  a20, a21, a22, a23)
        FMA4(6,  a24, a25, a26, a27)
        FMA4(7,  a28, a29, a30, a31)
        FMA4(8,  a32, a33, a34, a35)
        FMA4(9,  a36, a37, a38, a39)
        FMA4(10, a40, a41, a42, a43)
        FMA4(11, a44, a45, a46, a47)
        FMA4(12, a48, a49, a50, a51)
        FMA4(13, a52, a53, a54, a55)
        FMA4(14, a56, a57, a58, a59)
        FMA4(15, a60, a61, a62, a63)
    }

    // ---- cross-wave reduction: red[w][c][q] layout, lane-contiguous ----
    float* red = smem;   // reuse as [NWAVE][CCH][QBLK]
    REDUCE16(0, a0,a1,a2,a3,a4,a5,a6,a7,a8,a9,a10,a11,a12,a13,a14,a15)
    REDUCE16(1, a16,a17,a18,a19,a20,a21,a22,a23,a24,a25,a26,a27,a28,a29,a30,a31)
    REDUCE16(2, a32,a33,a34,a35,a36,a37,a38,a39,a40,a41,a42,a43,a44,a45,a46,a47)
    REDUCE16(3, a48,a49,a50,a51,a52,a53,a54,a55,a56,a57,a58,a59,a60,a61,a62,a63)

    // ---- esum reduction + per-query scalars ----
    __syncthreads();
    esred[wave][lane] = esum;
    __syncthreads();
    if (tid < QBLK) {
        float s = 0.f;
        #pragma unroll
        for (int w = 0; w < NWAVE; ++w) s += esred[w][tid];
        const float arg = ((-s) * dW[0] + db[0]) * 0.1f;
        qinfo[tid][1] = 1.f / (1.f + __expf(-arg));   // density channel
        qinfo[tid][0] = 1.f / s;                      // softmax denom
    }
    __syncthreads();

    // ---- fused resizer epilogue (normalization folded in) ----
    {
        const int qq   = tid >> 3;                // 0..63
        const float invE = qinfo[qq][0];
        const float dens = qinfo[qq][1];
        float* orow = out + (size_t)(b * NQ + q0 + qq) * COUT;
        #pragma unroll
        for (int r = 0; r < 8; ++r) {
            const int o = (tid & 7) + r * 8;
            const float* wrow = rW + o * (CIN + 1);
            float sdot = 0.f;
            #pragma unroll 8
            for (int c = 0; c < CIN; ++c) sdot += tot[qq][c] * wrow[c];
            orow[o] = rb[o] + dens * wrow[CIN] + sdot * invE;
        }
    }
}

extern "C" void kernel_launch(void* const* d_in, const int* in_sizes, int n_in,
                              void* d_out, int out_size, void* d_ws, size_t ws_size,
                              hipStream_t stream) {
    const float* keys    = (const float*)d_in[0];
    const float* queries = (const float*)d_in[1];
    const float* values  = (const float*)d_in[2];
    const float* wW      = (const float*)d_in[3];
    const float* lsp     = (const float*)d_in[4];
    const float* dW      = (const float*)d_in[5];
    const float* db      = (const float*)d_in[6];
    const float* rW      = (const float*)d_in[7];
    const float* rb      = (const float*)d_in[8];
    float* out = (float*)d_out;

    dim3 grid(B * (NQ / QBLK));   // 256 blocks
    setconv_kernel<<<grid, THREADS, 0, stream>>>(
        keys, queries, values, wW, lsp, dW, db, rW, rb, out);
}

// Round 5
// 63.803 us; speedup vs baseline: 5.7068x; 4.7654x over previous
//
#include <hip/hip_runtime.h>
#include <math.h>

#define B 8
#define NQ 2048
#define NK 2048
#define CIN 64
#define COUT 64

constexpr int THREADS = 512;           // 8 waves: 2 k-groups x 4 row-tiles
constexpr float LOG2E = 1.44269504088896340736f;

typedef __attribute__((ext_vector_type(8))) short bf16x8;
typedef __attribute__((ext_vector_type(4))) float f32x4;

__device__ __forceinline__ short f2bf(float x) {   // RNE f32->bf16 (finite values)
    union { float f; unsigned u; } v; v.f = x;
    return (short)((v.u + 0x7FFFu + ((v.u >> 16) & 1u)) >> 16);
}

// per-lane score j: e_j = exp2(Ek[k]+Fq + btil[k]*bq + atil[k]*aq), k = kb+j
#define SCORE(J, EV)                                              \
    float EV;                                                     \
    {                                                             \
        float t_ = ekl[kb + (J)] + Fq;                            \
        t_ = fmaf(btil[kb + (J)], bq, t_);                        \
        t_ = fmaf(atil[kb + (J)], aq, t_);                        \
        EV = exp2f(t_);                                           \
    }

// B fragment for col-tile CT: V[kb+j][CT*16 + l15], j=0..7, converted to bf16
#define BLOAD(BF, CT)                                             \
    bf16x8 BF;                                                    \
    BF[0] = f2bf(pB[0 * CIN + (CT) * 16]);                        \
    BF[1] = f2bf(pB[1 * CIN + (CT) * 16]);                        \
    BF[2] = f2bf(pB[2 * CIN + (CT) * 16]);                        \
    BF[3] = f2bf(pB[3 * CIN + (CT) * 16]);                        \
    BF[4] = f2bf(pB[4 * CIN + (CT) * 16]);                        \
    BF[5] = f2bf(pB[5 * CIN + (CT) * 16]);                        \
    BF[6] = f2bf(pB[6 * CIN + (CT) * 16]);                        \
    BF[7] = f2bf(pB[7 * CIN + (CT) * 16]);

__global__ __launch_bounds__(THREADS) void setconv_mfma(
    const float* __restrict__ keys,     // [B][NK][2]
    const float* __restrict__ queries,  // [B][NQ][2]
    const float* __restrict__ values,   // [B][NK][CIN]
    const float* __restrict__ wW,       // [2][2]
    const float* __restrict__ lsp,      // [1]
    const float* __restrict__ dW,       // [1]
    const float* __restrict__ db,       // [1]
    const float* __restrict__ rW,       // [COUT][CIN+1]
    const float* __restrict__ rb,       // [COUT]
    float* __restrict__ out)            // [B][NQ][COUT]
{
    __shared__ float atil[NK];              // 8 KB  score coefficients (SoA)
    __shared__ float btil[NK];              // 8 KB
    __shared__ float ekl[NK];               // 8 KB
    __shared__ float tot[64][66];           // 16.9 KB  combined P*V
    __shared__ float esum_lds[64];
    __shared__ float qinfo[64][2];          // inv_esum, density

    const int tid  = threadIdx.x;
    const int wave = tid >> 6;
    const int lane = tid & 63;
    const int g    = lane >> 4;             // 0..3 (k-subgroup within fragment)
    const int l15  = lane & 15;
    const int wg   = wave >> 2;             // 0/1: which 32-key substep
    const int rt   = wave & 3;              // row-tile (16 queries)

    const int bid = blockIdx.x;
    const int b   = bid & 7;                // batch == XCD (L2 locality)
    const int q0  = (bid >> 3) * 64;

    // uniform scalar params
    const float W00 = wW[0], W01 = wW[1], W10 = wW[2], W11 = wW[3];
    const float xls = lsp[0] * 0.1f - 1.0f;
    const float sp  = (xls > 20.f) ? xls : log1pf(__expf(xls));
    const float sigma = 1e-5f + sp;
    const float s2  = (-0.5f / (sigma * sigma)) * LOG2E;   // log2-domain scale

    // ---- phase 0: per-key score coefficients into LDS (SoA) ----
    {
        const float2* kb2 = (const float2*)(keys + (size_t)b * NK * 2);
        #pragma unroll
        for (int it = 0; it < NK / THREADS; ++it) {
            const int k = tid + it * THREADS;
            const float2 kv = kb2[k];
            const float a  = W00 * kv.x + W01 * kv.y;
            const float bb = W10 * kv.x + W11 * kv.y;
            atil[k] = -2.f * s2 * a;
            btil[k] = -2.f * s2 * bb;
            ekl[k]  = s2 * (a * a + bb * bb);
        }
    }

    // per-lane query coefficients (q = row of this lane's A fragment)
    const int q = q0 + rt * 16 + l15;
    const float2 qv = ((const float2*)(queries + (size_t)b * NQ * 2))[q];
    const float aq = W00 * qv.x + W01 * qv.y;
    const float bq = W10 * qv.x + W11 * qv.y;
    const float Fq = s2 * (aq * aq + bq * bq);

    __syncthreads();

    f32x4 c0 = {0.f, 0.f, 0.f, 0.f};
    f32x4 c1 = c0, c2 = c0, c3 = c0, ce = c0;
    const bf16x8 ones = { (short)0x3F80, (short)0x3F80, (short)0x3F80, (short)0x3F80,
                          (short)0x3F80, (short)0x3F80, (short)0x3F80, (short)0x3F80 };

    const float* vb = values + (size_t)b * NK * CIN;

    #pragma unroll 1
    for (int it = 0; it < NK / 64; ++it) {
        const int k0 = it * 64 + wg * 32;     // this group's 32-key substep
        const int kb = k0 + g * 8;            // this lane's first k

        // ---- A fragment: 8 scores, generated directly in fragment layout ----
        SCORE(0, e0) SCORE(1, e1) SCORE(2, e2) SCORE(3, e3)
        SCORE(4, e4) SCORE(5, e5) SCORE(6, e6) SCORE(7, e7)
        bf16x8 af;
        af[0] = f2bf(e0); af[1] = f2bf(e1); af[2] = f2bf(e2); af[3] = f2bf(e3);
        af[4] = f2bf(e4); af[5] = f2bf(e5); af[6] = f2bf(e6); af[7] = f2bf(e7);

        // ---- B fragments: V[k][c] straight from global (L1/L2-resident) ----
        const float* pB = vb + (size_t)kb * CIN + l15;
        BLOAD(b0, 0) BLOAD(b1, 1) BLOAD(b2, 2) BLOAD(b3, 3)

        c0 = __builtin_amdgcn_mfma_f32_16x16x32_bf16(af, b0, c0, 0, 0, 0);
        c1 = __builtin_amdgcn_mfma_f32_16x16x32_bf16(af, b1, c1, 0, 0, 0);
        c2 = __builtin_amdgcn_mfma_f32_16x16x32_bf16(af, b2, c2, 0, 0, 0);
        c3 = __builtin_amdgcn_mfma_f32_16x16x32_bf16(af, b3, c3, 0, 0, 0);
        ce = __builtin_amdgcn_mfma_f32_16x16x32_bf16(af, ones, ce, 0, 0, 0);
    }

    // ---- combine the two k-groups via LDS ----
    // C/D layout (m89-verified): col = lane&15, row = (lane>>4)*4 + reg
    #define STORE_R(R)                                                        \
    {                                                                         \
        const int qq = rt * 16 + g * 4 + (R);                                 \
        tot[qq][0 * 16 + l15] = c0[R];                                        \
        tot[qq][1 * 16 + l15] = c1[R];                                        \
        tot[qq][2 * 16 + l15] = c2[R];                                        \
        tot[qq][3 * 16 + l15] = c3[R];                                        \
        if (l15 == 0) esum_lds[qq] = ce[R];                                   \
    }
    #define ADD_R(R)                                                          \
    {                                                                         \
        const int qq = rt * 16 + g * 4 + (R);                                 \
        tot[qq][0 * 16 + l15] += c0[R];                                       \
        tot[qq][1 * 16 + l15] += c1[R];                                       \
        tot[qq][2 * 16 + l15] += c2[R];                                       \
        tot[qq][3 * 16 + l15] += c3[R];                                       \
        if (l15 == 0) esum_lds[qq] += ce[R];                                  \
    }
    if (wg == 0) { STORE_R(0) STORE_R(1) STORE_R(2) STORE_R(3) }
    __syncthreads();
    if (wg == 1) { ADD_R(0) ADD_R(1) ADD_R(2) ADD_R(3) }
    __syncthreads();

    // ---- per-query scalars ----
    if (tid < 64) {
        const float s = esum_lds[tid];
        const float arg = ((-s) * dW[0] + db[0]) * 0.1f;
        qinfo[tid][1] = 1.f / (1.f + __expf(-arg));   // density channel
        qinfo[tid][0] = 1.f / s;                      // softmax denom
    }
    __syncthreads();

    // ---- fused resizer epilogue (normalization folded in) ----
    {
        const int qq   = tid >> 3;                // 0..63
        const float invE = qinfo[qq][0];
        const float dens = qinfo[qq][1];
        float* orow = out + (size_t)(b * NQ + q0 + qq) * COUT;
        #pragma unroll
        for (int r = 0; r < 8; ++r) {
            const int o = (tid & 7) + r * 8;
            const float* wrow = rW + o * (CIN + 1);
            float sdot = 0.f;
            #pragma unroll 8
            for (int c = 0; c < CIN; ++c) sdot += tot[qq][c] * wrow[c];
            orow[o] = rb[o] + dens * wrow[CIN] + sdot * invE;
        }
    }
}

extern "C" void kernel_launch(void* const* d_in, const int* in_sizes, int n_in,
                              void* d_out, int out_size, void* d_ws, size_t ws_size,
                              hipStream_t stream) {
    const float* keys    = (const float*)d_in[0];
    const float* queries = (const float*)d_in[1];
    const float* values  = (const float*)d_in[2];
    const float* wW      = (const float*)d_in[3];
    const float* lsp     = (const float*)d_in[4];
    const float* dW      = (const float*)d_in[5];
    const float* db      = (const float*)d_in[6];
    const float* rW      = (const float*)d_in[7];
    const float* rb      = (const float*)d_in[8];
    float* out = (float*)d_out;
    (void)d_ws; (void)ws_size; (void)in_sizes; (void)n_in; (void)out_size;

    dim3 grid(B * (NQ / 64));   // 256 blocks
    setconv_mfma<<<grid, THREADS, 0, stream>>>(
        keys, queries, values, wW, lsp, dW, db, rW, rb, out);
}